// Round 1
// baseline (253.671 us; speedup 1.0000x reference)
//
#include <hip/hip_runtime.h>

#define T_ 4
#define B_ 8
#define C_ 256
#define H_ 32
#define W_ 32
#define TB_ 32
#define H2_ 16
#define W2_ 16
#define NB_ 16
#define SQRT2_ 1.4142135623730951
#define INVS2_ 0.7071067811865475
#define EPS_ 1e-5

// ---- workspace layout (bytes) ----
#define XS_OFF    ((size_t)0)          // u8  xs (T,B,C,H,W)            8 MB
#define H1C_OFF   ((size_t)8388608)    // i8  h1 codes (TB,2C,H,W2)     8 MB
#define H2G_OFF   ((size_t)16777216)   // f32 h2 gated (TB,4C,H2,W2)   32 MB
#define REC_OFF   ((size_t)50331648)   // f32 rec raw (TB,C,H,W)       32 MB
#define STATS_OFF ((size_t)83886080)
// stats doubles layout (indices into double*):
//   0..511    s1sum     512..1023  s1sq
//   1024..2047 s2sum    2048..3071 s2sq
//   3072..3327 s3sum    3328..3583 s3sq
//   3584..3839 s4sum    3840..4095 s4sq
//   4096..4351 s5sum    4352..4607 s5sq      (memset: 4608 doubles)
//   4608..5119 A1d      5120..5631 B1d
// floats at st+5632: A2[1024], B2[1024], P[1536] (A3,B3,A4,B4,A5,B5 x256)

// ============ K1: LIF (fp64 state) + W-Haar codes + BN1 stats ============
__global__ __launch_bounds__(256) void k1_lif(const float* __restrict__ x,
                                              unsigned char* __restrict__ xs,
                                              signed char* __restrict__ h1c,
                                              double* __restrict__ s1sum,
                                              double* __restrict__ s1sq) {
    const int bi = blockIdx.x;          // b*C + c
    const int b = bi >> 8;
    const int c = bi & 255;
    const int tid = threadIdx.x;
    int slo = 0, slo2 = 0, shi = 0, shi2 = 0;
    for (int rep = 0; rep < 2; ++rep) {
        const int pos = tid + rep * 256;          // h*16 + w2
        const int h = pos >> 4, w2 = pos & 15;
        double v0 = 0.0, v1 = 0.0;
        for (int t = 0; t < T_; ++t) {
            const size_t xi = ((size_t)((t * B_ + b) * C_ + c)) * 1024 + h * 32 + 2 * w2;
            const float x0 = x[xi], x1 = x[xi + 1];
            v0 += ((double)x0 - v0) / 2.0;
            v1 += ((double)x1 - v1) / 2.0;
            const int sp0 = (v0 - 1.0 >= 0.0) ? 1 : 0;
            const int sp1 = (v1 - 1.0 >= 0.0) ? 1 : 0;
            if (sp0) v0 = 0.0;
            if (sp1) v1 = 0.0;
            xs[xi] = (unsigned char)sp0;
            xs[xi + 1] = (unsigned char)sp1;
            const int lo = sp0 + sp1, hi = sp0 - sp1;
            const size_t hb = ((size_t)((t * B_ + b) * 512 + c)) * 512 + pos;
            h1c[hb] = (signed char)lo;
            h1c[hb + 256 * 512] = (signed char)hi;
            slo += lo; slo2 += lo * lo; shi += hi; shi2 += hi * hi;
        }
    }
    int vals[4] = {slo, slo2, shi, shi2};
    #pragma unroll
    for (int k = 0; k < 4; ++k) {
        int v = vals[k];
        for (int o = 32; o; o >>= 1) v += __shfl_down(v, o, 64);
        vals[k] = v;
    }
    __shared__ int sb[4][4];
    const int lane = tid & 63, wid = tid >> 6;
    if (lane == 0) { sb[0][wid] = vals[0]; sb[1][wid] = vals[1]; sb[2][wid] = vals[2]; sb[3][wid] = vals[3]; }
    __syncthreads();
    if (tid == 0) {
        int t0 = sb[0][0] + sb[0][1] + sb[0][2] + sb[0][3];
        int t1 = sb[1][0] + sb[1][1] + sb[1][2] + sb[1][3];
        int t2 = sb[2][0] + sb[2][1] + sb[2][2] + sb[2][3];
        int t3 = sb[3][0] + sb[3][1] + sb[3][2] + sb[3][3];
        atomicAdd(&s1sum[c], (double)t0);
        atomicAdd(&s1sq[c], (double)t1);
        atomicAdd(&s1sum[256 + c], (double)t2);
        atomicAdd(&s1sq[256 + c], (double)t3);
    }
}

// ============ K2: finalize BN1 ============
__global__ void k2_fin1(const double* __restrict__ s1sum, const double* __restrict__ s1sq,
                        const float* __restrict__ g, const float* __restrict__ bb,
                        double* __restrict__ A1d, double* __restrict__ B1d) {
    const int ch = blockIdx.x * 256 + threadIdx.x;   // 512
    const double n = 16384.0;
    const double sum = s1sum[ch] * INVS2_;           // codes -> values
    const double sq = s1sq[ch] * 0.5;
    const double m = sum / n;
    const double var = sq / n - m * m;
    const double a = (double)g[ch] / sqrt(var + EPS_);
    A1d[ch] = a * INVS2_;                            // value = code*A1d + B1d
    B1d[ch] = (double)bb[ch] - m * a;
}

// ============ K4: BN1 apply + H-Haar + coeff_gate + BN2/energy stats ============
__global__ __launch_bounds__(256) void k4_haar2(const signed char* __restrict__ h1c,
                                                const double* __restrict__ A1d,
                                                const double* __restrict__ B1d,
                                                float* __restrict__ h2g,
                                                double* __restrict__ s2sum,
                                                double* __restrict__ s2sq) {
    const int bi = blockIdx.x;            // tb*C + c
    const int tb = bi >> 8, c = bi & 255;
    const int tid = threadIdx.x;
    const int h2 = tid >> 4, w2 = tid & 15;
    const double Alo = A1d[c], Blo = B1d[c];
    const double Ahi = A1d[256 + c], Bhi = B1d[256 + c];
    const size_t lob = ((size_t)(tb * 512 + c)) * 512 + (2 * h2) * 16 + w2;
    const size_t hib = lob + (size_t)256 * 512;
    const double L0 = (double)h1c[lob] * Alo + Blo;
    const double L1 = (double)h1c[lob + 16] * Alo + Blo;
    const double Q0 = (double)h1c[hib] * Ahi + Bhi;
    const double Q1 = (double)h1c[hib + 16] * Ahi + Bhi;
    double LL = (L0 + L1) * INVS2_, HL = (L0 - L1) * INVS2_;
    double LH = (Q0 + Q1) * INVS2_, HH = (Q0 - Q1) * INVS2_;
    LL = (fabs(LL) - 0.5 >= 0.0) ? LL : 0.0;
    HL = (fabs(HL) - 0.5 >= 0.0) ? HL : 0.0;
    LH = (fabs(LH) - 0.5 >= 0.0) ? LH : 0.0;
    HH = (fabs(HH) - 0.5 >= 0.0) ? HH : 0.0;
    const size_t ob = ((size_t)(tb * 1024 + c)) * 256 + h2 * 16 + w2;
    h2g[ob] = (float)LL;
    h2g[ob + 256 * 256] = (float)HL;
    h2g[ob + 512 * 256] = (float)LH;
    h2g[ob + 768 * 256] = (float)HH;
    double v[8] = {LL, LL * LL, HL, HL * HL, LH, LH * LH, HH, HH * HH};
    __shared__ double sb[4];
    const int lane = tid & 63, wid = tid >> 6;
    for (int k = 0; k < 8; ++k) {
        double val = v[k];
        for (int o = 32; o; o >>= 1) val += __shfl_down(val, o, 64);
        __syncthreads();
        if (lane == 0) sb[wid] = val;
        __syncthreads();
        if (tid == 0) {
            const double tot = sb[0] + sb[1] + sb[2] + sb[3];
            const int ch = (k >> 1) * 256 + c;
            if (k & 1) atomicAdd(&s2sq[ch], tot);
            else       atomicAdd(&s2sum[ch], tot);
        }
    }
}

// ============ K5: finalize BN2 + channel energy gate ============
__global__ void k5_fin2(const double* __restrict__ s2sum, const double* __restrict__ s2sq,
                        const float* __restrict__ g, const float* __restrict__ bb,
                        float* __restrict__ A2, float* __restrict__ B2) {
    const int ch = blockIdx.x * 256 + threadIdx.x;  // 1024
    const double n = 8192.0;
    const double sum = s2sum[ch], sq = s2sq[ch];
    const double e = sq / n;
    const double tau = (ch < 256) ? 0.01 : (ch < 768 ? 0.02 : 0.05);
    if (e - tau >= 0.0) {
        const double m = sum / n;
        const double var = sq / n - m * m;
        const double a = (double)g[ch] / sqrt(var + EPS_);
        A2[ch] = (float)a;
        B2[ch] = (float)((double)bb[ch] - m * a);
    } else {
        A2[ch] = 0.0f;
        B2[ch] = bb[ch];
    }
}

// ============ K6: BN2 apply + block-diag matrix mix + inverse 2D Haar + BN3 stats ============
__global__ __launch_bounds__(256) void k6_mix(const float* __restrict__ h2g,
                                              const float* __restrict__ hw,
                                              const float* __restrict__ A2,
                                              const float* __restrict__ B2,
                                              float* __restrict__ rec,
                                              double* __restrict__ s3sum,
                                              double* __restrict__ s3sq) {
    const int bi = blockIdx.x;            // tb*256 + h2*16 + g
    const int tb = bi >> 8;
    const int rem = bi & 255;
    const int h2 = rem >> 4, g = rem & 15;
    const int tid = threadIdx.x;
    const int j = tid >> 4, w2 = tid & 15;
    const int nb0 = g >> 2;
    float wq[4][16];
    #pragma unroll
    for (int q = 0; q < 4; ++q) {
        const int nb = q * 4 + nb0;
        #pragma unroll
        for (int d = 0; d < 16; ++d) wq[q][d] = hw[(nb * 16 + d) * 16 + j];
    }
    float acc[4] = {0.f, 0.f, 0.f, 0.f};
    const size_t sb = (size_t)tb * 262144 + (size_t)(g * 16) * 256 + h2 * 16 + w2;
    #pragma unroll
    for (int d = 0; d < 16; ++d) {
        #pragma unroll
        for (int q = 0; q < 4; ++q) {
            const int ch = q * 256 + g * 16 + d;
            float vv = h2g[sb + (size_t)q * 65536 + (size_t)d * 256];
            vv = vv * A2[ch] + B2[ch];
            acc[q] += vv * wq[q][d];
        }
    }
    const float LL = acc[0], HL = acc[1], LH = acc[2], HH = acc[3];
    const float p00 = (LL + HL + LH + HH) * 0.5f;
    const float p01 = (LL + HL - LH - HH) * 0.5f;
    const float p10 = (LL - HL + LH - HH) * 0.5f;
    const float p11 = (LL - HL - LH + HH) * 0.5f;
    const int c = g * 16 + j;
    const size_t ob = ((size_t)(tb * 256 + c)) * 1024 + (size_t)(2 * h2) * 32 + 2 * w2;
    *(float2*)&rec[ob] = make_float2(p00, p01);
    *(float2*)&rec[ob + 32] = make_float2(p10, p11);
    double psum = (double)p00 + p01 + p10 + p11;
    double psq = (double)p00 * p00 + (double)p01 * p01 + (double)p10 * p10 + (double)p11 * p11;
    #pragma unroll
    for (int m = 1; m < 16; m <<= 1) {
        psum += __shfl_xor(psum, m, 64);
        psq += __shfl_xor(psq, m, 64);
    }
    if (w2 == 0) {
        atomicAdd(&s3sum[c], psum);
        atomicAdd(&s3sq[c], psq);
    }
}

// ============ conv kernels (stats pass + final apply pass) ============
template <bool FINAL>
__global__ __launch_bounds__(256) void kconv(const unsigned char* __restrict__ xs,
                                             const float* __restrict__ w1, const float* __restrict__ b1,
                                             const float* __restrict__ w2w, const float* __restrict__ b2,
                                             const float* __restrict__ rec, const float* __restrict__ P,
                                             float* __restrict__ out,
                                             double* __restrict__ s4sum, double* __restrict__ s4sq,
                                             double* __restrict__ s5sum, double* __restrict__ s5sq) {
    const int bi = blockIdx.x;           // tb*16 + nb
    const int tb = bi >> 4, nb = bi & 15;
    const int tid = threadIdx.x;
    const int dout = tid >> 4, prow = tid & 15;
    const int ch = nb * 16 + dout;
    __shared__ float tile[16 * 18 * 36];     // [d][row(-1..16)][col(-1..34)]
    double st1 = 0, st1q = 0, st2 = 0, st2q = 0;
    const float bias1 = b1[dout], bias2 = b2[dout];
    float a3 = 0, b3v = 0, a4 = 0, b4v = 0, a5 = 0, b5v = 0;
    if (FINAL) {
        a3 = P[ch]; b3v = P[256 + ch];
        a4 = P[512 + ch]; b4v = P[768 + ch];
        a5 = P[1024 + ch]; b5v = P[1280 + ch];
    }
    for (int ph = 0; ph < 2; ++ph) {
        if (ph) __syncthreads();
        for (int idx = tid; idx < 10368; idx += 256) {
            const int d = idx / 648;
            const int rm = idx % 648;
            const int r = rm / 36, cp = rm % 36;
            const int gh = ph * 16 + r - 1, gw = cp - 1;
            float val = 0.f;
            if ((unsigned)gh < 32u && (unsigned)gw < 32u)
                val = (float)xs[((size_t)(tb * 256 + nb * 16 + d)) * 1024 + gh * 32 + gw];
            tile[idx] = val;
        }
        __syncthreads();
        float acc2[32], acc1[32];
        #pragma unroll
        for (int w = 0; w < 32; ++w) { acc2[w] = 0.f; acc1[w] = 0.f; }
        for (int d = 0; d < 16; ++d) {
            const float* wp = &w2w[(dout * 16 + d) * 9];
            float w9[9];
            #pragma unroll
            for (int k = 0; k < 9; ++k) w9[k] = wp[k];
            const float w1v = w1[dout * 16 + d];
            const float* trow = &tile[(d * 18 + prow) * 36];
            #pragma unroll
            for (int dy = 0; dy < 3; ++dy) {
                float rv[36];
                const float4* rp = (const float4*)&trow[dy * 36];
                #pragma unroll
                for (int k = 0; k < 9; ++k) {
                    const float4 t4 = rp[k];
                    rv[4 * k] = t4.x; rv[4 * k + 1] = t4.y; rv[4 * k + 2] = t4.z; rv[4 * k + 3] = t4.w;
                }
                #pragma unroll
                for (int dx = 0; dx < 3; ++dx) {
                    const float wv = w9[dy * 3 + dx];
                    #pragma unroll
                    for (int w = 0; w < 32; ++w) acc2[w] += wv * rv[w + dx];
                }
                if (dy == 1) {
                    #pragma unroll
                    for (int w = 0; w < 32; ++w) acc1[w] += w1v * rv[w + 1];
                }
            }
        }
        const int h = ph * 16 + prow;
        if (FINAL) {
            const size_t base = ((size_t)(tb * 256 + ch)) * 1024 + (size_t)h * 32;
            #pragma unroll
            for (int w = 0; w < 32; w += 4) {
                const float4 r4 = *(const float4*)&rec[base + w];
                float4 o;
                o.x = a3 * r4.x + b3v + a4 * (acc1[w] + bias1) + b4v + a5 * (acc2[w] + bias2) + b5v;
                o.y = a3 * r4.y + b3v + a4 * (acc1[w + 1] + bias1) + b4v + a5 * (acc2[w + 1] + bias2) + b5v;
                o.z = a3 * r4.z + b3v + a4 * (acc1[w + 2] + bias1) + b4v + a5 * (acc2[w + 2] + bias2) + b5v;
                o.w = a3 * r4.w + b3v + a4 * (acc1[w + 3] + bias1) + b4v + a5 * (acc2[w + 3] + bias2) + b5v;
                *(float4*)&out[base + w] = o;
            }
        } else {
            #pragma unroll
            for (int w = 0; w < 32; ++w) {
                const float c1v = acc1[w] + bias1, c2v = acc2[w] + bias2;
                st1 += c1v; st1q += (double)c1v * c1v;
                st2 += c2v; st2q += (double)c2v * c2v;
            }
        }
    }
    if (!FINAL) {
        #pragma unroll
        for (int m = 1; m < 16; m <<= 1) {
            st1 += __shfl_xor(st1, m, 64);
            st1q += __shfl_xor(st1q, m, 64);
            st2 += __shfl_xor(st2, m, 64);
            st2q += __shfl_xor(st2q, m, 64);
        }
        if (prow == 0) {
            atomicAdd(&s4sum[ch], st1);
            atomicAdd(&s4sq[ch], st1q);
            atomicAdd(&s5sum[ch], st2);
            atomicAdd(&s5sq[ch], st2q);
        }
    }
}

// ============ K8: finalize BN3 (rec) + BN4 (conv1) + BN5 (conv2) ============
__global__ void k8_fin3(const double* __restrict__ s3sum, const double* __restrict__ s3sq,
                        const double* __restrict__ s4sum, const double* __restrict__ s4sq,
                        const double* __restrict__ s5sum, const double* __restrict__ s5sq,
                        const float* __restrict__ g3, const float* __restrict__ b3,
                        const float* __restrict__ g4, const float* __restrict__ b4,
                        const float* __restrict__ g5, const float* __restrict__ b5,
                        float* __restrict__ P) {
    const int ch = threadIdx.x;   // 256
    const double n = 32768.0;
    {
        const double m = s3sum[ch] / n, var = s3sq[ch] / n - m * m;
        const double a = (double)g3[ch] / sqrt(var + EPS_);
        P[ch] = (float)a; P[256 + ch] = (float)((double)b3[ch] - m * a);
    }
    {
        const double m = s4sum[ch] / n, var = s4sq[ch] / n - m * m;
        const double a = (double)g4[ch] / sqrt(var + EPS_);
        P[512 + ch] = (float)a; P[768 + ch] = (float)((double)b4[ch] - m * a);
    }
    {
        const double m = s5sum[ch] / n, var = s5sq[ch] / n - m * m;
        const double a = (double)g5[ch] / sqrt(var + EPS_);
        P[1024 + ch] = (float)a; P[1280 + ch] = (float)((double)b5[ch] - m * a);
    }
}

extern "C" void kernel_launch(void* const* d_in, const int* in_sizes, int n_in,
                              void* d_out, int out_size, void* d_ws, size_t ws_size,
                              hipStream_t stream) {
    const float* x        = (const float*)d_in[0];
    const float* haar_w   = (const float*)d_in[1];
    const float* conv1_w  = (const float*)d_in[2];
    const float* conv1_b  = (const float*)d_in[3];
    const float* conv2_w  = (const float*)d_in[4];
    const float* conv2_b  = (const float*)d_in[5];
    const float* g_fwd    = (const float*)d_in[6];
    const float* b_fwd    = (const float*)d_in[7];
    const float* g_mul    = (const float*)d_in[8];
    const float* b_mul    = (const float*)d_in[9];
    const float* g_inv    = (const float*)d_in[10];
    const float* b_inv    = (const float*)d_in[11];
    const float* g_c1     = (const float*)d_in[12];
    const float* b_c1     = (const float*)d_in[13];
    const float* g_c2     = (const float*)d_in[14];
    const float* b_c2     = (const float*)d_in[15];
    float* out = (float*)d_out;

    char* ws = (char*)d_ws;
    unsigned char* xs = (unsigned char*)(ws + XS_OFF);
    signed char* h1c  = (signed char*)(ws + H1C_OFF);
    float* h2g        = (float*)(ws + H2G_OFF);
    float* rec        = (float*)(ws + REC_OFF);
    double* st        = (double*)(ws + STATS_OFF);
    double* s1sum = st,        * s1sq = st + 512;
    double* s2sum = st + 1024, * s2sq = st + 2048;
    double* s3sum = st + 3072, * s3sq = st + 3328;
    double* s4sum = st + 3584, * s4sq = st + 3840;
    double* s5sum = st + 4096, * s5sq = st + 4352;
    double* A1d = st + 4608, * B1d = st + 5120;
    float* fp = (float*)(st + 5632);
    float* A2 = fp;
    float* B2 = fp + 1024;
    float* P  = fp + 2048;

    hipMemsetAsync(st, 0, 4608 * sizeof(double), stream);

    k1_lif<<<dim3(B_ * C_), dim3(256), 0, stream>>>(x, xs, h1c, s1sum, s1sq);
    k2_fin1<<<dim3(2), dim3(256), 0, stream>>>(s1sum, s1sq, g_fwd, b_fwd, A1d, B1d);
    k4_haar2<<<dim3(TB_ * C_), dim3(256), 0, stream>>>(h1c, A1d, B1d, h2g, s2sum, s2sq);
    k5_fin2<<<dim3(4), dim3(256), 0, stream>>>(s2sum, s2sq, g_mul, b_mul, A2, B2);
    k6_mix<<<dim3(TB_ * H2_ * 16), dim3(256), 0, stream>>>(h2g, haar_w, A2, B2, rec, s3sum, s3sq);
    kconv<false><<<dim3(TB_ * NB_), dim3(256), 0, stream>>>(xs, conv1_w, conv1_b, conv2_w, conv2_b,
                                                            nullptr, nullptr, nullptr,
                                                            s4sum, s4sq, s5sum, s5sq);
    k8_fin3<<<dim3(1), dim3(256), 0, stream>>>(s3sum, s3sq, s4sum, s4sq, s5sum, s5sq,
                                               g_inv, b_inv, g_c1, b_c1, g_c2, b_c2, P);
    kconv<true><<<dim3(TB_ * NB_), dim3(256), 0, stream>>>(xs, conv1_w, conv1_b, conv2_w, conv2_b,
                                                           rec, P, out,
                                                           s4sum, s4sq, s5sum, s5sq);
}

// Round 2
// 151.195 us; speedup vs baseline: 1.6778x; 1.6778x over previous
//
#include <hip/hip_runtime.h>

#define T_ 4
#define B_ 8
#define C_ 256
#define H_ 32
#define W_ 32
#define TB_ 32
#define H2_ 16
#define W2_ 16
#define NB_ 16
#define SQRT2_ 1.4142135623730951
#define INVS2_ 0.7071067811865475
#define EPS_ 1e-5

typedef __attribute__((ext_vector_type(8))) short short8;
typedef __attribute__((ext_vector_type(4))) float f32x4;

// ---- workspace layout (bytes) ----
#define XS_OFF    ((size_t)0)          // u8  xs (T,B,C,H,W)            8 MB
#define H1C_OFF   ((size_t)8388608)    // i8  h1 codes (TB,2C,H,W2)     8 MB
#define H2G_OFF   ((size_t)16777216)   // f32 h2 gated (TB,4C,H2,W2)   32 MB
#define REC_OFF   ((size_t)50331648)   // f32 rec raw (TB,C,H,W)       32 MB
#define STATS_OFF ((size_t)83886080)

__device__ __forceinline__ unsigned short f2bf(float v) {
    union { float f; unsigned u; } x; x.f = v;
    unsigned r = x.u + 0x7FFFu + ((x.u >> 16) & 1u);
    return (unsigned short)(r >> 16);
}

// ============ K1: LIF (fp64 state) + W-Haar codes + BN1 stats ============
__global__ __launch_bounds__(256) void k1_lif(const float* __restrict__ x,
                                              unsigned char* __restrict__ xs,
                                              signed char* __restrict__ h1c,
                                              double* __restrict__ s1sum,
                                              double* __restrict__ s1sq) {
    const int bi = blockIdx.x;          // b*C + c
    const int b = bi >> 8;
    const int c = bi & 255;
    const int tid = threadIdx.x;
    int slo = 0, slo2 = 0, shi = 0, shi2 = 0;
    for (int rep = 0; rep < 2; ++rep) {
        const int pos = tid + rep * 256;          // h*16 + w2
        const int h = pos >> 4, w2 = pos & 15;
        double v0 = 0.0, v1 = 0.0;
        for (int t = 0; t < T_; ++t) {
            const size_t xi = ((size_t)((t * B_ + b) * C_ + c)) * 1024 + h * 32 + 2 * w2;
            const float x0 = x[xi], x1 = x[xi + 1];
            v0 += ((double)x0 - v0) / 2.0;
            v1 += ((double)x1 - v1) / 2.0;
            const int sp0 = (v0 - 1.0 >= 0.0) ? 1 : 0;
            const int sp1 = (v1 - 1.0 >= 0.0) ? 1 : 0;
            if (sp0) v0 = 0.0;
            if (sp1) v1 = 0.0;
            xs[xi] = (unsigned char)sp0;
            xs[xi + 1] = (unsigned char)sp1;
            const int lo = sp0 + sp1, hi = sp0 - sp1;
            const size_t hb = ((size_t)((t * B_ + b) * 512 + c)) * 512 + pos;
            h1c[hb] = (signed char)lo;
            h1c[hb + 256 * 512] = (signed char)hi;
            slo += lo; slo2 += lo * lo; shi += hi; shi2 += hi * hi;
        }
    }
    int vals[4] = {slo, slo2, shi, shi2};
    #pragma unroll
    for (int k = 0; k < 4; ++k) {
        int v = vals[k];
        for (int o = 32; o; o >>= 1) v += __shfl_down(v, o, 64);
        vals[k] = v;
    }
    __shared__ int sb[4][4];
    const int lane = tid & 63, wid = tid >> 6;
    if (lane == 0) { sb[0][wid] = vals[0]; sb[1][wid] = vals[1]; sb[2][wid] = vals[2]; sb[3][wid] = vals[3]; }
    __syncthreads();
    if (tid == 0) {
        int t0 = sb[0][0] + sb[0][1] + sb[0][2] + sb[0][3];
        int t1 = sb[1][0] + sb[1][1] + sb[1][2] + sb[1][3];
        int t2 = sb[2][0] + sb[2][1] + sb[2][2] + sb[2][3];
        int t3 = sb[3][0] + sb[3][1] + sb[3][2] + sb[3][3];
        atomicAdd(&s1sum[c], (double)t0);
        atomicAdd(&s1sq[c], (double)t1);
        atomicAdd(&s1sum[256 + c], (double)t2);
        atomicAdd(&s1sq[256 + c], (double)t3);
    }
}

// ============ K2: finalize BN1 ============
__global__ void k2_fin1(const double* __restrict__ s1sum, const double* __restrict__ s1sq,
                        const float* __restrict__ g, const float* __restrict__ bb,
                        double* __restrict__ A1d, double* __restrict__ B1d) {
    const int ch = blockIdx.x * 256 + threadIdx.x;   // 512
    const double n = 16384.0;
    const double sum = s1sum[ch] * INVS2_;
    const double sq = s1sq[ch] * 0.5;
    const double m = sum / n;
    const double var = sq / n - m * m;
    const double a = (double)g[ch] / sqrt(var + EPS_);
    A1d[ch] = a * INVS2_;
    B1d[ch] = (double)bb[ch] - m * a;
}

// ============ K4: BN1 apply + H-Haar + coeff_gate + BN2/energy stats ============
__global__ __launch_bounds__(256) void k4_haar2(const signed char* __restrict__ h1c,
                                                const double* __restrict__ A1d,
                                                const double* __restrict__ B1d,
                                                float* __restrict__ h2g,
                                                double* __restrict__ s2sum,
                                                double* __restrict__ s2sq) {
    const int bi = blockIdx.x;            // tb*C + c
    const int tb = bi >> 8, c = bi & 255;
    const int tid = threadIdx.x;
    const int h2 = tid >> 4, w2 = tid & 15;
    const double Alo = A1d[c], Blo = B1d[c];
    const double Ahi = A1d[256 + c], Bhi = B1d[256 + c];
    const size_t lob = ((size_t)(tb * 512 + c)) * 512 + (2 * h2) * 16 + w2;
    const size_t hib = lob + (size_t)256 * 512;
    const double L0 = (double)h1c[lob] * Alo + Blo;
    const double L1 = (double)h1c[lob + 16] * Alo + Blo;
    const double Q0 = (double)h1c[hib] * Ahi + Bhi;
    const double Q1 = (double)h1c[hib + 16] * Ahi + Bhi;
    double LL = (L0 + L1) * INVS2_, HL = (L0 - L1) * INVS2_;
    double LH = (Q0 + Q1) * INVS2_, HH = (Q0 - Q1) * INVS2_;
    LL = (fabs(LL) - 0.5 >= 0.0) ? LL : 0.0;
    HL = (fabs(HL) - 0.5 >= 0.0) ? HL : 0.0;
    LH = (fabs(LH) - 0.5 >= 0.0) ? LH : 0.0;
    HH = (fabs(HH) - 0.5 >= 0.0) ? HH : 0.0;
    const size_t ob = ((size_t)(tb * 1024 + c)) * 256 + h2 * 16 + w2;
    h2g[ob] = (float)LL;
    h2g[ob + 256 * 256] = (float)HL;
    h2g[ob + 512 * 256] = (float)LH;
    h2g[ob + 768 * 256] = (float)HH;
    double v[8] = {LL, LL * LL, HL, HL * HL, LH, LH * LH, HH, HH * HH};
    __shared__ double sb[4];
    const int lane = tid & 63, wid = tid >> 6;
    for (int k = 0; k < 8; ++k) {
        double val = v[k];
        for (int o = 32; o; o >>= 1) val += __shfl_down(val, o, 64);
        __syncthreads();
        if (lane == 0) sb[wid] = val;
        __syncthreads();
        if (tid == 0) {
            const double tot = sb[0] + sb[1] + sb[2] + sb[3];
            const int ch = (k >> 1) * 256 + c;
            if (k & 1) atomicAdd(&s2sq[ch], tot);
            else       atomicAdd(&s2sum[ch], tot);
        }
    }
}

// ============ K5: finalize BN2 + channel energy gate ============
__global__ void k5_fin2(const double* __restrict__ s2sum, const double* __restrict__ s2sq,
                        const float* __restrict__ g, const float* __restrict__ bb,
                        float* __restrict__ A2, float* __restrict__ B2) {
    const int ch = blockIdx.x * 256 + threadIdx.x;  // 1024
    const double n = 8192.0;
    const double sum = s2sum[ch], sq = s2sq[ch];
    const double e = sq / n;
    const double tau = (ch < 256) ? 0.01 : (ch < 768 ? 0.02 : 0.05);
    if (e - tau >= 0.0) {
        const double m = sum / n;
        const double var = sq / n - m * m;
        const double a = (double)g[ch] / sqrt(var + EPS_);
        A2[ch] = (float)a;
        B2[ch] = (float)((double)bb[ch] - m * a);
    } else {
        A2[ch] = 0.0f;
        B2[ch] = bb[ch];
    }
}

// ============ K6: BN2 apply + block-diag mix + inverse 2D Haar + BN3 stats ============
__global__ __launch_bounds__(256) void k6_mix(const float* __restrict__ h2g,
                                              const float* __restrict__ hw,
                                              const float* __restrict__ A2,
                                              const float* __restrict__ B2,
                                              float* __restrict__ rec,
                                              double* __restrict__ s3sum,
                                              double* __restrict__ s3sq) {
    const int bi = blockIdx.x;            // tb*256 + h2*16 + g
    const int tb = bi >> 8;
    const int rem = bi & 255;
    const int h2 = rem >> 4, g = rem & 15;
    const int tid = threadIdx.x;
    const int j = tid >> 4, w2 = tid & 15;
    const int nb0 = g >> 2;
    float wq[4][16];
    #pragma unroll
    for (int q = 0; q < 4; ++q) {
        const int nb = q * 4 + nb0;
        #pragma unroll
        for (int d = 0; d < 16; ++d) wq[q][d] = hw[(nb * 16 + d) * 16 + j];
    }
    float acc[4] = {0.f, 0.f, 0.f, 0.f};
    const size_t sb = (size_t)tb * 262144 + (size_t)(g * 16) * 256 + h2 * 16 + w2;
    #pragma unroll
    for (int d = 0; d < 16; ++d) {
        #pragma unroll
        for (int q = 0; q < 4; ++q) {
            const int ch = q * 256 + g * 16 + d;
            float vv = h2g[sb + (size_t)q * 65536 + (size_t)d * 256];
            vv = vv * A2[ch] + B2[ch];
            acc[q] += vv * wq[q][d];
        }
    }
    const float LL = acc[0], HL = acc[1], LH = acc[2], HH = acc[3];
    const float p00 = (LL + HL + LH + HH) * 0.5f;
    const float p01 = (LL + HL - LH - HH) * 0.5f;
    const float p10 = (LL - HL + LH - HH) * 0.5f;
    const float p11 = (LL - HL - LH + HH) * 0.5f;
    const int c = g * 16 + j;
    const size_t ob = ((size_t)(tb * 256 + c)) * 1024 + (size_t)(2 * h2) * 32 + 2 * w2;
    *(float2*)&rec[ob] = make_float2(p00, p01);
    *(float2*)&rec[ob + 32] = make_float2(p10, p11);
    double psum = (double)p00 + p01 + p10 + p11;
    double psq = (double)p00 * p00 + (double)p01 * p01 + (double)p10 * p10 + (double)p11 * p11;
    #pragma unroll
    for (int m = 1; m < 16; m <<= 1) {
        psum += __shfl_xor(psum, m, 64);
        psq += __shfl_xor(psq, m, 64);
    }
    if (w2 == 0) {
        atomicAdd(&s3sum[c], psum);
        atomicAdd(&s3sq[c], psq);
    }
}

// ============ MFMA conv: stats pass (FINAL=0) + fused output pass (FINAL=1) ============
// conv2: 3x3 16->16ch; conv1: 1x1 16->16ch; input xs is binary u8.
// LDS tile: [r 0..33][c 0..33][d 0..15] bf16 (halo, zero-padded), bit-4 XOR swizzle.
// Per 16-pixel row-tile: 5 MFMA (tap pairs, k = tap_local*16 + d) + 1 MFMA (conv1).
template <bool FINAL>
__global__ __launch_bounds__(256) void kconv_mfma(
        const unsigned char* __restrict__ xs,
        const float* __restrict__ w1, const float* __restrict__ b1v,
        const float* __restrict__ w2w, const float* __restrict__ b2v,
        const float* __restrict__ rec, const float* __restrict__ P,
        float* __restrict__ out,
        double* __restrict__ s4sum, double* __restrict__ s4sq,
        double* __restrict__ s5sum, double* __restrict__ s5sq) {
    const int tb = blockIdx.x >> 4, nb = blockIdx.x & 15;
    const int tid = threadIdx.x;
    const int lane = tid & 63, wid = tid >> 6;
    __shared__ __align__(16) unsigned short tile[34 * 34 * 16];   // 36992 B

    // ---- stage xs -> LDS bf16 [r][c][d], swizzled ----
    const size_t xbase = (size_t)(tb * 256 + nb * 16) * 1024;
    for (int it = 0; it < 5; ++it) {
        const int idx = tid + it * 256;
        if (idx < 34 * 34) {
            const int r = idx / 34, c = idx % 34;
            const int gh = r - 1, gw = c - 1;
            unsigned v[8] = {0u, 0u, 0u, 0u, 0u, 0u, 0u, 0u};
            if (((unsigned)gh < 32u) & ((unsigned)gw < 32u)) {
                const size_t p = xbase + gh * 32 + gw;
                #pragma unroll
                for (int dp = 0; dp < 8; ++dp) {
                    const unsigned lo = xs[p + (size_t)(2 * dp) * 1024];
                    const unsigned hi = xs[p + (size_t)(2 * dp + 1) * 1024];
                    v[dp] = (lo ? 0x3F80u : 0u) | (hi ? 0x3F800000u : 0u);
                }
            }
            const int base = (r * 34 + c) * 32;
            const int sw = (c & 4) << 2;
            *(uint4*)((char*)tile + ((base)      ^ sw)) = make_uint4(v[0], v[1], v[2], v[3]);
            *(uint4*)((char*)tile + ((base + 16) ^ sw)) = make_uint4(v[4], v[5], v[6], v[7]);
        }
    }

    // ---- A fragments (weights, bf16) ----
    const int o = lane & 15, g = lane >> 4;
    const int dA = (g & 1) * 8;
    short8 awc2[5], awc1;
    #pragma unroll
    for (int m = 0; m < 5; ++m) {
        const int t = (m < 4) ? (2 * m + (g >> 1)) : 8;
        const bool act = (m < 4) || (g < 2);
        #pragma unroll
        for (int j = 0; j < 8; ++j) {
            const float wv = act ? w2w[(o * 16 + dA + j) * 9 + t] : 0.0f;
            awc2[m][j] = (short)f2bf(wv);
        }
    }
    #pragma unroll
    for (int j = 0; j < 8; ++j) {
        const float wv = (g < 2) ? w1[o * 16 + dA + j] : 0.0f;
        awc1[j] = (short)f2bf(wv);
    }

    // ---- per-lane epilogue constants ----
    float A3[4], A4[4], A5[4], KK[4];
    if (FINAL) {
        #pragma unroll
        for (int r = 0; r < 4; ++r) {
            const int oc = g * 4 + r;            // C/D row = out channel
            const int ch = nb * 16 + oc;
            A3[r] = P[ch]; A4[r] = P[512 + ch]; A5[r] = P[1024 + ch];
            KK[r] = P[256 + ch] + P[768 + ch] + P[1280 + ch]
                  + A4[r] * b1v[oc] + A5[r] * b2v[oc];
        }
    }
    double t1s[4] = {0, 0, 0, 0}, t1q[4] = {0, 0, 0, 0};
    double t2s[4] = {0, 0, 0, 0}, t2q[4] = {0, 0, 0, 0};

    __syncthreads();

    const int n = lane & 15;
    for (int ti = 0; ti < 16; ++ti) {
        const int h = wid * 8 + (ti >> 1);
        const int w0 = (ti & 1) * 16;
        short8 bf[6];
        #pragma unroll
        for (int m = 0; m < 6; ++m) {
            const int t = (m < 4) ? (2 * m + (g >> 1)) : ((m == 4) ? 8 : 4);
            const int ky = t / 3, kx = t % 3;
            const int rr = h + ky, cc = w0 + n + kx;
            const int addr = (((rr * 34 + cc) * 32) + dA * 2) ^ ((cc & 4) << 2);
            bf[m] = *(const short8*)((const char*)tile + addr);
        }
        f32x4 acc2 = {0.f, 0.f, 0.f, 0.f};
        #pragma unroll
        for (int m = 0; m < 5; ++m)
            acc2 = __builtin_amdgcn_mfma_f32_16x16x32_bf16(awc2[m], bf[m], acc2, 0, 0, 0);
        const f32x4 z = {0.f, 0.f, 0.f, 0.f};
        const f32x4 acc1 = __builtin_amdgcn_mfma_f32_16x16x32_bf16(awc1, bf[5], z, 0, 0, 0);

        if (FINAL) {
            #pragma unroll
            for (int r = 0; r < 4; ++r) {
                const int oc = g * 4 + r;
                const size_t ai = ((size_t)(tb * 256 + nb * 16 + oc)) * 1024
                                + (size_t)h * 32 + w0 + n;
                out[ai] = A3[r] * rec[ai] + A4[r] * acc1[r] + A5[r] * acc2[r] + KK[r];
            }
        } else {
            #pragma unroll
            for (int r = 0; r < 4; ++r) {
                t1s[r] += acc1[r]; t1q[r] += (double)acc1[r] * acc1[r];
                t2s[r] += acc2[r]; t2q[r] += (double)acc2[r] * acc2[r];
            }
        }
    }

    if (!FINAL) {
        #pragma unroll
        for (int r = 0; r < 4; ++r) {
            #pragma unroll
            for (int m = 1; m < 16; m <<= 1) {
                t1s[r] += __shfl_xor(t1s[r], m, 64);
                t1q[r] += __shfl_xor(t1q[r], m, 64);
                t2s[r] += __shfl_xor(t2s[r], m, 64);
                t2q[r] += __shfl_xor(t2q[r], m, 64);
            }
        }
        if ((lane & 15) == 0) {
            #pragma unroll
            for (int r = 0; r < 4; ++r) {
                const int ch = nb * 16 + g * 4 + r;
                atomicAdd(&s4sum[ch], t1s[r]);
                atomicAdd(&s4sq[ch], t1q[r]);
                atomicAdd(&s5sum[ch], t2s[r]);
                atomicAdd(&s5sq[ch], t2q[r]);
            }
        }
    }
}

// ============ K8: finalize BN3 (rec) + BN4 (conv1, bias-folded) + BN5 (conv2) ============
__global__ void k8_fin3(const double* __restrict__ s3sum, const double* __restrict__ s3sq,
                        const double* __restrict__ s4sum, const double* __restrict__ s4sq,
                        const double* __restrict__ s5sum, const double* __restrict__ s5sq,
                        const float* __restrict__ g3, const float* __restrict__ b3,
                        const float* __restrict__ g4, const float* __restrict__ b4,
                        const float* __restrict__ g5, const float* __restrict__ b5,
                        const float* __restrict__ c1b, const float* __restrict__ c2b,
                        float* __restrict__ P) {
    const int ch = threadIdx.x;   // 256
    const double n = 32768.0;
    {
        const double m = s3sum[ch] / n, var = s3sq[ch] / n - m * m;
        const double a = (double)g3[ch] / sqrt(var + EPS_);
        P[ch] = (float)a; P[256 + ch] = (float)((double)b3[ch] - m * a);
    }
    {
        const double bias = (double)c1b[ch & 15];
        const double sum = s4sum[ch] + n * bias;
        const double sq = s4sq[ch] + 2.0 * bias * s4sum[ch] + n * bias * bias;
        const double m = sum / n, var = sq / n - m * m;
        const double a = (double)g4[ch] / sqrt(var + EPS_);
        P[512 + ch] = (float)a; P[768 + ch] = (float)((double)b4[ch] - m * a);
    }
    {
        const double bias = (double)c2b[ch & 15];
        const double sum = s5sum[ch] + n * bias;
        const double sq = s5sq[ch] + 2.0 * bias * s5sum[ch] + n * bias * bias;
        const double m = sum / n, var = sq / n - m * m;
        const double a = (double)g5[ch] / sqrt(var + EPS_);
        P[1024 + ch] = (float)a; P[1280 + ch] = (float)((double)b5[ch] - m * a);
    }
}

extern "C" void kernel_launch(void* const* d_in, const int* in_sizes, int n_in,
                              void* d_out, int out_size, void* d_ws, size_t ws_size,
                              hipStream_t stream) {
    const float* x        = (const float*)d_in[0];
    const float* haar_w   = (const float*)d_in[1];
    const float* conv1_w  = (const float*)d_in[2];
    const float* conv1_b  = (const float*)d_in[3];
    const float* conv2_w  = (const float*)d_in[4];
    const float* conv2_b  = (const float*)d_in[5];
    const float* g_fwd    = (const float*)d_in[6];
    const float* b_fwd    = (const float*)d_in[7];
    const float* g_mul    = (const float*)d_in[8];
    const float* b_mul    = (const float*)d_in[9];
    const float* g_inv    = (const float*)d_in[10];
    const float* b_inv    = (const float*)d_in[11];
    const float* g_c1     = (const float*)d_in[12];
    const float* b_c1     = (const float*)d_in[13];
    const float* g_c2     = (const float*)d_in[14];
    const float* b_c2     = (const float*)d_in[15];
    float* out = (float*)d_out;

    char* ws = (char*)d_ws;
    unsigned char* xs = (unsigned char*)(ws + XS_OFF);
    signed char* h1c  = (signed char*)(ws + H1C_OFF);
    float* h2g        = (float*)(ws + H2G_OFF);
    float* rec        = (float*)(ws + REC_OFF);
    double* st        = (double*)(ws + STATS_OFF);
    double* s1sum = st,        * s1sq = st + 512;
    double* s2sum = st + 1024, * s2sq = st + 2048;
    double* s3sum = st + 3072, * s3sq = st + 3328;
    double* s4sum = st + 3584, * s4sq = st + 3840;
    double* s5sum = st + 4096, * s5sq = st + 4352;
    double* A1d = st + 4608, * B1d = st + 5120;
    float* fp = (float*)(st + 5632);
    float* A2 = fp;
    float* B2 = fp + 1024;
    float* P  = fp + 2048;

    hipMemsetAsync(st, 0, 4608 * sizeof(double), stream);

    k1_lif<<<dim3(B_ * C_), dim3(256), 0, stream>>>(x, xs, h1c, s1sum, s1sq);
    k2_fin1<<<dim3(2), dim3(256), 0, stream>>>(s1sum, s1sq, g_fwd, b_fwd, A1d, B1d);
    k4_haar2<<<dim3(TB_ * C_), dim3(256), 0, stream>>>(h1c, A1d, B1d, h2g, s2sum, s2sq);
    k5_fin2<<<dim3(4), dim3(256), 0, stream>>>(s2sum, s2sq, g_mul, b_mul, A2, B2);
    k6_mix<<<dim3(TB_ * H2_ * 16), dim3(256), 0, stream>>>(h2g, haar_w, A2, B2, rec, s3sum, s3sq);
    kconv_mfma<false><<<dim3(TB_ * NB_), dim3(256), 0, stream>>>(
        xs, conv1_w, conv1_b, conv2_w, conv2_b, nullptr, nullptr, nullptr,
        s4sum, s4sq, s5sum, s5sq);
    k8_fin3<<<dim3(1), dim3(256), 0, stream>>>(s3sum, s3sq, s4sum, s4sq, s5sum, s5sq,
                                               g_inv, b_inv, g_c1, b_c1, g_c2, b_c2,
                                               conv1_b, conv2_b, P);
    kconv_mfma<true><<<dim3(TB_ * NB_), dim3(256), 0, stream>>>(
        xs, conv1_w, conv1_b, conv2_w, conv2_b, rec, P, out,
        s4sum, s4sq, s5sum, s5sq);
}

// Round 3
// 95.104 us; speedup vs baseline: 2.6673x; 1.5898x over previous
//
#include <hip/hip_runtime.h>

#define T_ 4
#define B_ 8
#define C_ 256
#define TB_ 32
#define SQRT2_ 1.4142135623730951
#define INVS2_ 0.7071067811865475
#define EPS_ 1e-5

typedef __attribute__((ext_vector_type(8))) short short8;
typedef __attribute__((ext_vector_type(4))) float f32x4;

// ---- workspace layout ----
#define XS_OFF   ((size_t)0)          // u8 xs (T,B,C,32,32)   8 MB
#define H1C_OFF  ((size_t)8388608)    // i8 h1 codes           8 MB
#define ST_OFF   ((size_t)16777216)   // doubles stats
// stats (double indices)
#define S1S 0
#define S1Q 512
#define S2S 1024
#define S2Q 2048
#define S3S 3072
#define S3Q 3328
#define S4S 3584
#define S4Q 3840
#define S5S 4096
#define S5Q 4352
#define NST 4608

__device__ __forceinline__ unsigned short f2bf(float v) {
    union { float f; unsigned u; } x; x.f = v;
    unsigned r = x.u + 0x7FFFu + ((x.u >> 16) & 1u);
    return (unsigned short)(r >> 16);
}

// BN1 params (channel ch in [0,512)); A includes *INVS2 (value = code*A + B)
__device__ __forceinline__ void bn1p(const double* __restrict__ st, int ch,
                                     const float* __restrict__ g, const float* __restrict__ bb,
                                     double& A, double& Bv) {
    const double sum = st[S1S + ch] * INVS2_;
    const double sq  = st[S1Q + ch] * 0.5;
    const double m = sum / 16384.0;
    const double var = sq / 16384.0 - m * m;
    const double a = (double)g[ch] / sqrt(var + EPS_);
    A = a * INVS2_;
    Bv = (double)bb[ch] - m * a;
}

// BN2 params + channel energy gate (ch in [0,1024))
__device__ __forceinline__ void bn2p(const double* __restrict__ st, int ch,
                                     const float* __restrict__ g, const float* __restrict__ bb,
                                     float& A, float& Bv) {
    const double sum = st[S2S + ch], sq = st[S2Q + ch];
    const double e = sq / 8192.0;
    const double tau = (ch < 256) ? 0.01 : (ch < 768 ? 0.02 : 0.05);
    if (e - tau >= 0.0) {
        const double m = sum / 8192.0;
        const double var = sq / 8192.0 - m * m;
        const double a = (double)g[ch] / sqrt(var + EPS_);
        A = (float)a; Bv = (float)((double)bb[ch] - m * a);
    } else { A = 0.0f; Bv = bb[ch]; }
}

// ============ K1: LIF (fp64) -> xs(u8), h1c(i8) + BN1 stats ============
__global__ __launch_bounds__(256) void k1_lif(const float* __restrict__ x,
                                              unsigned char* __restrict__ xs,
                                              signed char* __restrict__ h1c,
                                              double* __restrict__ st) {
    const int b = blockIdx.x >> 6, cg = blockIdx.x & 63;
    const int tid = threadIdx.x, wid = tid >> 6, lane = tid & 63;
    const int c = cg * 4 + wid;
    const int h = lane >> 1, wseg = (lane & 1) * 16;
    double v[16];
    #pragma unroll
    for (int i = 0; i < 16; ++i) v[i] = 0.0;
    int slo = 0, slo2 = 0, shi = 0, shi2 = 0;
    for (int t = 0; t < T_; ++t) {
        const size_t xi = ((size_t)((t * 8 + b) * 256 + c)) * 1024 + h * 32 + wseg;
        const float4* xp = (const float4*)(x + xi);
        unsigned spk[4], lo8[2], hi8[2];
        #pragma unroll
        for (int q4 = 0; q4 < 4; ++q4) {
            const float4 xv = xp[q4];
            int sp[4];
            #pragma unroll
            for (int e = 0; e < 4; ++e) {
                const double xd = (e == 0 ? xv.x : e == 1 ? xv.y : e == 2 ? xv.z : xv.w);
                double vv = v[q4 * 4 + e];
                vv = vv + (xd - vv) * 0.5;
                const int s = (vv - 1.0 >= 0.0) ? 1 : 0;
                if (s) vv = 0.0;
                v[q4 * 4 + e] = vv;
                sp[e] = s;
            }
            spk[q4] = (unsigned)(sp[0] | (sp[1] << 8) | (sp[2] << 16) | (sp[3] << 24));
            const int lo0 = sp[0] + sp[1], lo1 = sp[2] + sp[3];
            const int hi0 = sp[0] - sp[1], hi1 = sp[2] - sp[3];
            slo += lo0 + lo1; slo2 += lo0 * lo0 + lo1 * lo1;
            shi += hi0 + hi1; shi2 += hi0 * hi0 + hi1 * hi1;
            const unsigned lb = (unsigned)((lo0 & 0xFF) | ((lo1 & 0xFF) << 8));
            const unsigned hb = (unsigned)((hi0 & 0xFF) | ((hi1 & 0xFF) << 8));
            if (q4 == 0) { lo8[0] = lb; hi8[0] = hb; }
            else if (q4 == 1) { lo8[0] |= lb << 16; hi8[0] |= hb << 16; }
            else if (q4 == 2) { lo8[1] = lb; hi8[1] = hb; }
            else { lo8[1] |= lb << 16; hi8[1] |= hb << 16; }
        }
        *(uint4*)(xs + xi) = make_uint4(spk[0], spk[1], spk[2], spk[3]);
        const size_t lob = ((size_t)((t * 8 + b) * 512 + c)) * 512 + h * 16 + (lane & 1) * 8;
        const size_t hib = ((size_t)((t * 8 + b) * 512 + 256 + c)) * 512 + h * 16 + (lane & 1) * 8;
        *(uint2*)(h1c + lob) = make_uint2(lo8[0], lo8[1]);
        *(uint2*)(h1c + hib) = make_uint2(hi8[0], hi8[1]);
    }
    int vals[4] = {slo, slo2, shi, shi2};
    #pragma unroll
    for (int k = 0; k < 4; ++k)
        #pragma unroll
        for (int m = 1; m < 64; m <<= 1) vals[k] += __shfl_xor(vals[k], m, 64);
    if (lane == 0) {
        atomicAdd(&st[S1S + c], (double)vals[0]);
        atomicAdd(&st[S1Q + c], (double)vals[1]);
        atomicAdd(&st[S1S + 256 + c], (double)vals[2]);
        atomicAdd(&st[S1Q + 256 + c], (double)vals[3]);
    }
}

// ============ K4s: BN2/energy stats from h1c ============
__global__ __launch_bounds__(256) void k4s(const signed char* __restrict__ h1c,
                                           double* __restrict__ st,
                                           const float* __restrict__ g_fwd,
                                           const float* __restrict__ b_fwd) {
    const int tb = blockIdx.x >> 6, cg = blockIdx.x & 63;
    const int tid = threadIdx.x, wid = tid >> 6, lane = tid & 63;
    const int c = cg * 4 + wid;
    __shared__ double A1s[8], B1s[8];
    if (tid < 8) {
        const int cl = cg * 4 + (tid & 3), band = tid >> 2;
        double A, Bv; bn1p(st, band * 256 + cl, g_fwd, b_fwd, A, Bv);
        A1s[tid] = A; B1s[tid] = Bv;
    }
    __syncthreads();
    const double Alo = A1s[wid], Blo = B1s[wid];
    const double Ahi = A1s[4 + wid], Bhi = B1s[4 + wid];
    const int h2 = lane >> 2, w2b = (lane & 3) * 4;
    const size_t lob = ((size_t)(tb * 512 + c)) * 512 + (2 * h2) * 16 + w2b;
    const size_t hib = ((size_t)(tb * 512 + 256 + c)) * 512 + (2 * h2) * 16 + w2b;
    const unsigned la = *(const unsigned*)(h1c + lob);
    const unsigned lb = *(const unsigned*)(h1c + lob + 16);
    const unsigned qa = *(const unsigned*)(h1c + hib);
    const unsigned qb = *(const unsigned*)(h1c + hib + 16);
    double acc[8] = {0, 0, 0, 0, 0, 0, 0, 0};
    #pragma unroll
    for (int m = 0; m < 4; ++m) {
        const int l0 = (int)(signed char)(la >> (8 * m));
        const int l1 = (int)(signed char)(lb >> (8 * m));
        const int q0 = (int)(signed char)(qa >> (8 * m));
        const int q1 = (int)(signed char)(qb >> (8 * m));
        const double L0 = (double)l0 * Alo + Blo;
        const double L1 = (double)l1 * Alo + Blo;
        const double Q0 = (double)q0 * Ahi + Bhi;
        const double Q1 = (double)q1 * Ahi + Bhi;
        double LL = (L0 + L1) * INVS2_, HL = (L0 - L1) * INVS2_;
        double LH = (Q0 + Q1) * INVS2_, HH = (Q0 - Q1) * INVS2_;
        LL = (fabs(LL) - 0.5 >= 0.0) ? LL : 0.0;
        HL = (fabs(HL) - 0.5 >= 0.0) ? HL : 0.0;
        LH = (fabs(LH) - 0.5 >= 0.0) ? LH : 0.0;
        HH = (fabs(HH) - 0.5 >= 0.0) ? HH : 0.0;
        acc[0] += LL; acc[1] += LL * LL;
        acc[2] += HL; acc[3] += HL * HL;
        acc[4] += LH; acc[5] += LH * LH;
        acc[6] += HH; acc[7] += HH * HH;
    }
    #pragma unroll
    for (int k = 0; k < 8; ++k)
        #pragma unroll
        for (int m = 1; m < 64; m <<= 1) acc[k] += __shfl_xor(acc[k], m, 64);
    if (lane == 0) {
        #pragma unroll
        for (int q = 0; q < 4; ++q) {
            atomicAdd(&st[S2S + q * 256 + c], acc[2 * q]);
            atomicAdd(&st[S2Q + q * 256 + c], acc[2 * q + 1]);
        }
    }
}

// ---- coef phase: recompute gated, BN2-applied coefficients -> LDS bf16 ----
// coefL layout: [pair(2)][pos(256)][kk(32)] bf16, 16B-slot swizzled: slot ^= pos&3
__device__ __forceinline__ void coef_phaseA(const signed char* __restrict__ h1c, int tb, int gb, int tid,
                                            const double* A1L, const double* B1L,
                                            const float* A2L, const float* B2L,
                                            unsigned short* coefL) {
    const int h2 = tid >> 4, w2 = tid & 15;
    const int P = tid;
    unsigned pk[4][8];
    #pragma unroll
    for (int d = 0; d < 16; ++d) {
        const int c = gb * 16 + d;
        const size_t lob = ((size_t)(tb * 512 + c)) * 512 + (2 * h2) * 16 + w2;
        const size_t hib = ((size_t)(tb * 512 + 256 + c)) * 512 + (2 * h2) * 16 + w2;
        const double Alo = A1L[d], Blo = B1L[d];
        const double Ahi = A1L[16 + d], Bhi = B1L[16 + d];
        const double L0 = (double)h1c[lob] * Alo + Blo;
        const double L1 = (double)h1c[lob + 16] * Alo + Blo;
        const double Q0 = (double)h1c[hib] * Ahi + Bhi;
        const double Q1 = (double)h1c[hib + 16] * Ahi + Bhi;
        double LL = (L0 + L1) * INVS2_, HL = (L0 - L1) * INVS2_;
        double LH = (Q0 + Q1) * INVS2_, HH = (Q0 - Q1) * INVS2_;
        LL = (fabs(LL) - 0.5 >= 0.0) ? LL : 0.0;
        HL = (fabs(HL) - 0.5 >= 0.0) ? HL : 0.0;
        LH = (fabs(LH) - 0.5 >= 0.0) ? LH : 0.0;
        HH = (fabs(HH) - 0.5 >= 0.0) ? HH : 0.0;
        const float vq0 = fmaf((float)LL, A2L[d],      B2L[d]);
        const float vq1 = fmaf((float)HL, A2L[16 + d], B2L[16 + d]);
        const float vq2 = fmaf((float)LH, A2L[32 + d], B2L[32 + d]);
        const float vq3 = fmaf((float)HH, A2L[48 + d], B2L[48 + d]);
        const unsigned h0 = f2bf(vq0), h1v = f2bf(vq1), h2v = f2bf(vq2), h3 = f2bf(vq3);
        if (d & 1) {
            pk[0][d >> 1] |= h0 << 16; pk[1][d >> 1] |= h1v << 16;
            pk[2][d >> 1] |= h2v << 16; pk[3][d >> 1] |= h3 << 16;
        } else {
            pk[0][d >> 1] = h0; pk[1][d >> 1] = h1v;
            pk[2][d >> 1] = h2v; pk[3][d >> 1] = h3;
        }
    }
    #pragma unroll
    for (int q = 0; q < 4; ++q) {
        const int pair = q >> 1;
        #pragma unroll
        for (int db = 0; db < 2; ++db) {
            const int slot = (((q & 1) * 2 + db) ^ (P & 3));
            char* dst = (char*)coefL + pair * 16384 + P * 64 + slot * 16;
            *(uint4*)dst = make_uint4(pk[q][db * 4], pk[q][db * 4 + 1], pk[q][db * 4 + 2], pk[q][db * 4 + 3]);
        }
    }
}

// ---- mix A-fragments: half-zeroed haar weights per quadrant ----
__device__ __forceinline__ void mix_frags(const float* __restrict__ hw, int gb, int lane, short8 am[4]) {
    const int o = lane & 15, g = lane >> 4;
    #pragma unroll
    for (int q = 0; q < 4; ++q) {
        #pragma unroll
        for (int e = 0; e < 8; ++e) {
            const int kk = g * 8 + e;
            unsigned short v = 0;
            if ((kk >> 4) == (q & 1)) {
                const int d = kk & 15;
                const int nbp = q * 4 + (gb >> 2);
                v = f2bf(hw[(nbp * 16 + d) * 16 + o]);
            }
            am[q][e] = (short)v;
        }
    }
}

// ---- mix one h2-row: 2 ds_read + 4 MFMA -> Mh[q] (row j=(lane>>4)*4+r, col w2=lane&15) ----
__device__ __forceinline__ void mix_hh(const unsigned short* coefL, const short8 am[4],
                                       int lane, int wid, int hh, f32x4 Mh[4]) {
    const int o = lane & 15, g = lane >> 4;
    const int P = (wid * 4 + hh) * 16 + o;
    #pragma unroll
    for (int p = 0; p < 2; ++p) {
        const int slot = g ^ (P & 3);
        const short8 bf = *(const short8*)((const char*)coefL + p * 16384 + P * 64 + slot * 16);
        const f32x4 z = {0.f, 0.f, 0.f, 0.f};
        Mh[2 * p]     = __builtin_amdgcn_mfma_f32_16x16x32_bf16(am[2 * p], bf, z, 0, 0, 0);
        Mh[2 * p + 1] = __builtin_amdgcn_mfma_f32_16x16x32_bf16(am[2 * p + 1], bf, z, 0, 0, 0);
    }
}

// ---- conv tile staging: xs -> LDS bf16 [r][c][d], (c&4)<<2 swizzle ----
__device__ __forceinline__ void stage_tile(const unsigned char* __restrict__ xs, int tb, int gb, int tid,
                                           unsigned short* tile) {
    const size_t xbase = (size_t)(tb * 256 + gb * 16) * 1024;
    for (int it = 0; it < 5; ++it) {
        const int idx = tid + it * 256;
        if (idx < 34 * 34) {
            const int r = idx / 34, c = idx % 34;
            const int gh = r - 1, gw = c - 1;
            unsigned v[8] = {0u, 0u, 0u, 0u, 0u, 0u, 0u, 0u};
            if (((unsigned)gh < 32u) & ((unsigned)gw < 32u)) {
                const size_t p = xbase + gh * 32 + gw;
                #pragma unroll
                for (int dp = 0; dp < 8; ++dp) {
                    const unsigned b0 = xs[p + (size_t)(2 * dp) * 1024];
                    const unsigned b1 = xs[p + (size_t)(2 * dp + 1) * 1024];
                    v[dp] = (b0 | (b1 << 16)) * 0x3F80u;
                }
            }
            const int base = (r * 34 + c) * 32;
            const int sw = (c & 4) << 2;
            *(uint4*)((char*)tile + (base ^ sw)) = make_uint4(v[0], v[1], v[2], v[3]);
            *(uint4*)((char*)tile + ((base + 16) ^ sw)) = make_uint4(v[4], v[5], v[6], v[7]);
        }
    }
}

__device__ __forceinline__ void conv_frags(const float* __restrict__ w1, const float* __restrict__ w2w,
                                           int lane, short8* awc2, short8& awc1) {
    const int o = lane & 15, g = lane >> 4, dA = (g & 1) * 8;
    #pragma unroll
    for (int m = 0; m < 5; ++m) {
        const int t = (m < 4) ? (2 * m + (g >> 1)) : 8;
        const bool act = (m < 4) || (g < 2);
        #pragma unroll
        for (int j = 0; j < 8; ++j) {
            const float wv = act ? w2w[(o * 16 + dA + j) * 9 + t] : 0.0f;
            awc2[m][j] = (short)f2bf(wv);
        }
    }
    #pragma unroll
    for (int j = 0; j < 8; ++j) {
        const float wv = (g < 2) ? w1[o * 16 + dA + j] : 0.0f;
        awc1[j] = (short)f2bf(wv);
    }
}

__device__ __forceinline__ void conv_tile(const unsigned short* tile, int lane, int h, int w0,
                                          const short8* awc2, const short8& awc1,
                                          f32x4& acc2o, f32x4& acc1o) {
    const int g = lane >> 4, n = lane & 15, dA = (g & 1) * 8;
    short8 bf[6];
    #pragma unroll
    for (int m = 0; m < 6; ++m) {
        const int t = (m < 4) ? (2 * m + (g >> 1)) : ((m == 4) ? 8 : 4);
        const int ky = t / 3, kx = t % 3;
        const int rr = h + ky, cc = w0 + n + kx;
        const int addr = (((rr * 34 + cc) * 32) + dA * 2) ^ ((cc & 4) << 2);
        bf[m] = *(const short8*)((const char*)tile + addr);
    }
    f32x4 acc2 = {0.f, 0.f, 0.f, 0.f};
    #pragma unroll
    for (int m = 0; m < 5; ++m)
        acc2 = __builtin_amdgcn_mfma_f32_16x16x32_bf16(awc2[m], bf[m], acc2, 0, 0, 0);
    const f32x4 z = {0.f, 0.f, 0.f, 0.f};
    acc1o = __builtin_amdgcn_mfma_f32_16x16x32_bf16(awc1, bf[5], z, 0, 0, 0);
    acc2o = acc2;
}

// ============ KMID: blocks [0,512): BN3 stats via mix-MFMA; [512,1024): conv stats ============
__global__ __launch_bounds__(256) void kmid(const unsigned char* __restrict__ xs,
                                            const signed char* __restrict__ h1c,
                                            double* __restrict__ st,
                                            const float* __restrict__ haar_w,
                                            const float* __restrict__ g_fwd, const float* __restrict__ b_fwd,
                                            const float* __restrict__ g_mul, const float* __restrict__ b_mul,
                                            const float* __restrict__ conv1_w, const float* __restrict__ conv2_w) {
    __shared__ __align__(16) char smem[37504];
    const int tid = threadIdx.x, lane = tid & 63, wid = tid >> 6;
    if (blockIdx.x < 512) {
        const int tb = blockIdx.x >> 4, gb = blockIdx.x & 15;
        double* A1L = (double*)smem;
        double* B1L = (double*)(smem + 256);
        float* A2L = (float*)(smem + 512);
        float* B2L = (float*)(smem + 768);
        float* padd = (float*)(smem + 1024);               // [4][16][2]
        unsigned short* coefL = (unsigned short*)(smem + 1536);
        if (tid < 32) {
            const int d = tid & 15, band = tid >> 4;
            double A, Bv; bn1p(st, band * 256 + gb * 16 + d, g_fwd, b_fwd, A, Bv);
            A1L[tid] = A; B1L[tid] = Bv;
        } else if (tid < 96) {
            const int k = tid - 32, q = k >> 4, d = k & 15;
            float A, Bv; bn2p(st, q * 256 + gb * 16 + d, g_mul, b_mul, A, Bv);
            A2L[k] = A; B2L[k] = Bv;
        }
        __syncthreads();
        coef_phaseA(h1c, tb, gb, tid, A1L, B1L, A2L, B2L, coefL);
        short8 am[4];
        mix_frags(haar_w, gb, lane, am);
        __syncthreads();
        float s2x[4] = {0, 0, 0, 0}, se[4] = {0, 0, 0, 0};
        #pragma unroll
        for (int hh = 0; hh < 4; ++hh) {
            f32x4 Mh[4];
            mix_hh(coefL, am, lane, wid, hh, Mh);
            #pragma unroll
            for (int r = 0; r < 4; ++r) {
                s2x[r] += 2.0f * Mh[0][r];
                #pragma unroll
                for (int q = 0; q < 4; ++q) se[r] += Mh[q][r] * Mh[q][r];
            }
        }
        #pragma unroll
        for (int r = 0; r < 4; ++r)
            #pragma unroll
            for (int m = 1; m < 16; m <<= 1) {
                s2x[r] += __shfl_xor(s2x[r], m, 64);
                se[r]  += __shfl_xor(se[r], m, 64);
            }
        const int G = lane >> 4;
        if ((lane & 15) == 0) {
            #pragma unroll
            for (int r = 0; r < 4; ++r) {
                padd[(wid * 16 + G * 4 + r) * 2]     = s2x[r];
                padd[(wid * 16 + G * 4 + r) * 2 + 1] = se[r];
            }
        }
        __syncthreads();
        if (tid < 32) {
            const int j = tid >> 1, s = tid & 1;
            const float tot = padd[(0 * 16 + j) * 2 + s] + padd[(1 * 16 + j) * 2 + s]
                            + padd[(2 * 16 + j) * 2 + s] + padd[(3 * 16 + j) * 2 + s];
            atomicAdd(&st[(s ? S3Q : S3S) + gb * 16 + j], (double)tot);
        }
    } else {
        const int bid = blockIdx.x - 512;
        const int tb = bid >> 4, gb = bid & 15;
        unsigned short* tile = (unsigned short*)smem;
        stage_tile(xs, tb, gb, tid, tile);
        short8 awc2[5], awc1;
        conv_frags(conv1_w, conv2_w, lane, awc2, awc1);
        __syncthreads();
        double t1s[4] = {0, 0, 0, 0}, t1q[4] = {0, 0, 0, 0};
        double t2s[4] = {0, 0, 0, 0}, t2q[4] = {0, 0, 0, 0};
        for (int ti = 0; ti < 16; ++ti) {
            const int h = wid * 8 + (ti >> 1), w0 = (ti & 1) * 16;
            f32x4 a2v, a1v;
            conv_tile(tile, lane, h, w0, awc2, awc1, a2v, a1v);
            #pragma unroll
            for (int r = 0; r < 4; ++r) {
                t1s[r] += a1v[r]; t1q[r] += (double)a1v[r] * a1v[r];
                t2s[r] += a2v[r]; t2q[r] += (double)a2v[r] * a2v[r];
            }
        }
        #pragma unroll
        for (int r = 0; r < 4; ++r)
            #pragma unroll
            for (int m = 1; m < 16; m <<= 1) {
                t1s[r] += __shfl_xor(t1s[r], m, 64);
                t1q[r] += __shfl_xor(t1q[r], m, 64);
                t2s[r] += __shfl_xor(t2s[r], m, 64);
                t2q[r] += __shfl_xor(t2q[r], m, 64);
            }
        if ((lane & 15) == 0) {
            const int G = lane >> 4;
            #pragma unroll
            for (int r = 0; r < 4; ++r) {
                const int ch = gb * 16 + G * 4 + r;
                atomicAdd(&st[S4S + ch], t1s[r]);
                atomicAdd(&st[S4Q + ch], t1q[r]);
                atomicAdd(&st[S5S + ch], t2s[r]);
                atomicAdd(&st[S5Q + ch], t2q[r]);
            }
        }
    }
}

// ============ KFIN: mix + inverse Haar + convs + 3xBN epilogue -> out ============
__global__ __launch_bounds__(256) void kfin(const unsigned char* __restrict__ xs,
                                            const signed char* __restrict__ h1c,
                                            const double* __restrict__ st,
                                            const float* __restrict__ haar_w,
                                            const float* __restrict__ g_fwd, const float* __restrict__ b_fwd,
                                            const float* __restrict__ g_mul, const float* __restrict__ b_mul,
                                            const float* __restrict__ g_inv, const float* __restrict__ b_inv,
                                            const float* __restrict__ g_c1, const float* __restrict__ b_c1,
                                            const float* __restrict__ g_c2, const float* __restrict__ b_c2,
                                            const float* __restrict__ conv1_w, const float* __restrict__ conv1_b,
                                            const float* __restrict__ conv2_w, const float* __restrict__ conv2_b,
                                            float* __restrict__ out) {
    __shared__ __align__(16) char smem[71040];
    const int tid = threadIdx.x, lane = tid & 63, wid = tid >> 6;
    const int tb = blockIdx.x >> 4, gb = blockIdx.x & 15;
    double* A1L = (double*)smem;
    double* B1L = (double*)(smem + 256);
    float* A2L = (float*)(smem + 512);
    float* B2L = (float*)(smem + 768);
    float* PA3 = (float*)(smem + 1024);
    float* PA4 = PA3 + 16; float* PA5 = PA3 + 32; float* PK = PA3 + 48;
    unsigned short* coefL = (unsigned short*)(smem + 1280);
    unsigned short* tile  = (unsigned short*)(smem + 1280 + 32768);
    if (tid < 32) {
        const int d = tid & 15, band = tid >> 4;
        double A, Bv; bn1p(st, band * 256 + gb * 16 + d, g_fwd, b_fwd, A, Bv);
        A1L[tid] = A; B1L[tid] = Bv;
    } else if (tid < 96) {
        const int k = tid - 32, q = k >> 4, d = k & 15;
        float A, Bv; bn2p(st, q * 256 + gb * 16 + d, g_mul, b_mul, A, Bv);
        A2L[k] = A; B2L[k] = Bv;
    } else if (tid < 112) {
        const int oc = tid - 96, c = gb * 16 + oc;
        const double n3 = 32768.0;
        const double m3 = st[S3S + c] / n3, var3 = st[S3Q + c] / n3 - m3 * m3;
        const double a3 = (double)g_inv[c] / sqrt(var3 + EPS_);
        const double bias1 = (double)conv1_b[oc];
        const double s4 = st[S4S + c] + n3 * bias1;
        const double q4v = st[S4Q + c] + 2.0 * bias1 * st[S4S + c] + n3 * bias1 * bias1;
        const double m4 = s4 / n3, var4 = q4v / n3 - m4 * m4;
        const double a4 = (double)g_c1[c] / sqrt(var4 + EPS_);
        const double bias2 = (double)conv2_b[oc];
        const double s5 = st[S5S + c] + n3 * bias2;
        const double q5v = st[S5Q + c] + 2.0 * bias2 * st[S5S + c] + n3 * bias2 * bias2;
        const double m5 = s5 / n3, var5 = q5v / n3 - m5 * m5;
        const double a5 = (double)g_c2[c] / sqrt(var5 + EPS_);
        PA3[oc] = (float)a3; PA4[oc] = (float)a4; PA5[oc] = (float)a5;
        PK[oc] = (float)(((double)b_inv[c] - m3 * a3) + ((double)b_c1[c] - m4 * a4)
                       + ((double)b_c2[c] - m5 * a5) + a4 * bias1 + a5 * bias2);
    }
    __syncthreads();
    stage_tile(xs, tb, gb, tid, tile);
    coef_phaseA(h1c, tb, gb, tid, A1L, B1L, A2L, B2L, coefL);
    short8 am[4], awc2[5], awc1;
    mix_frags(haar_w, gb, lane, am);
    conv_frags(conv1_w, conv2_w, lane, awc2, awc1);
    __syncthreads();
    const int G = lane >> 4, n = lane & 15;
    float fA3[4], fA4[4], fA5[4], fK[4];
    #pragma unroll
    for (int r = 0; r < 4; ++r) {
        const int oc = G * 4 + r;
        fA3[r] = PA3[oc]; fA4[r] = PA4[oc]; fA5[r] = PA5[oc]; fK[r] = PK[oc];
    }
    const float sw = (n & 1) ? -1.0f : 1.0f;
    #pragma unroll
    for (int hh = 0; hh < 4; ++hh) {
        f32x4 Mh[4];
        mix_hh(coefL, am, lane, wid, hh, Mh);
        #pragma unroll
        for (int w0h = 0; w0h < 2; ++w0h) {
            const int src = (lane & 48) + w0h * 8 + (n >> 1);
            float ms[4][4];
            #pragma unroll
            for (int q = 0; q < 4; ++q)
                #pragma unroll
                for (int r = 0; r < 4; ++r) ms[q][r] = __shfl(Mh[q][r], src, 64);
            #pragma unroll
            for (int hrow = 0; hrow < 2; ++hrow) {
                const float sh = hrow ? -1.0f : 1.0f;
                const int h = wid * 8 + hh * 2 + hrow;
                const int w0 = w0h * 16;
                f32x4 a2v, a1v;
                conv_tile(tile, lane, h, w0, awc2, awc1, a2v, a1v);
                #pragma unroll
                for (int r = 0; r < 4; ++r) {
                    const float rec = 0.5f * ((ms[0][r] + sh * ms[1][r]) + sw * (ms[2][r] + sh * ms[3][r]));
                    const int oc = G * 4 + r;
                    const size_t ai = ((size_t)(tb * 256 + gb * 16 + oc)) * 1024 + (size_t)h * 32 + w0 + n;
                    out[ai] = fA3[r] * rec + fA4[r] * a1v[r] + fA5[r] * a2v[r] + fK[r];
                }
            }
        }
    }
}

extern "C" void kernel_launch(void* const* d_in, const int* in_sizes, int n_in,
                              void* d_out, int out_size, void* d_ws, size_t ws_size,
                              hipStream_t stream) {
    const float* x        = (const float*)d_in[0];
    const float* haar_w   = (const float*)d_in[1];
    const float* conv1_w  = (const float*)d_in[2];
    const float* conv1_b  = (const float*)d_in[3];
    const float* conv2_w  = (const float*)d_in[4];
    const float* conv2_b  = (const float*)d_in[5];
    const float* g_fwd    = (const float*)d_in[6];
    const float* b_fwd    = (const float*)d_in[7];
    const float* g_mul    = (const float*)d_in[8];
    const float* b_mul    = (const float*)d_in[9];
    const float* g_inv    = (const float*)d_in[10];
    const float* b_inv    = (const float*)d_in[11];
    const float* g_c1     = (const float*)d_in[12];
    const float* b_c1     = (const float*)d_in[13];
    const float* g_c2     = (const float*)d_in[14];
    const float* b_c2     = (const float*)d_in[15];
    float* out = (float*)d_out;

    char* ws = (char*)d_ws;
    unsigned char* xs = (unsigned char*)(ws + XS_OFF);
    signed char* h1c  = (signed char*)(ws + H1C_OFF);
    double* st        = (double*)(ws + ST_OFF);

    hipMemsetAsync(st, 0, NST * sizeof(double), stream);
    k1_lif<<<dim3(512), dim3(256), 0, stream>>>(x, xs, h1c, st);
    k4s<<<dim3(2048), dim3(256), 0, stream>>>(h1c, st, g_fwd, b_fwd);
    kmid<<<dim3(1024), dim3(256), 0, stream>>>(xs, h1c, st, haar_w, g_fwd, b_fwd,
                                               g_mul, b_mul, conv1_w, conv2_w);
    kfin<<<dim3(512), dim3(256), 0, stream>>>(xs, h1c, st, haar_w, g_fwd, b_fwd, g_mul, b_mul,
                                              g_inv, b_inv, g_c1, b_c1, g_c2, b_c2,
                                              conv1_w, conv1_b, conv2_w, conv2_b, out);
}